// Round 5
// baseline (532.084 us; speedup 1.0000x reference)
//
#include <hip/hip_runtime.h>
#include <hip/hip_bf16.h>
#include <math.h>

#define KD 128
#define NS 4096
#define NE 4096
#define NK 128
#define NNODE (NS + NE + NK)      // 8320
#define ESE 131072
#define EEK 16384
#define NCSR (2*ESE + 2*EEK)      // 294912
#define BQ 8192
#define RP (NNODE + 1)
#define HB 32                     // CSR-build blocks per graph

typedef __attribute__((ext_vector_type(8))) short short8;   // 8 bf16 (4 VGPRs)
typedef __attribute__((ext_vector_type(4))) float float4_;  // 4 fp32 acc

__device__ __forceinline__ float lrelu_(float x){ return x >= 0.f ? x : 0.2f*x; }
__device__ __forceinline__ float elu_(float x){ return x > 0.f ? x : __expf(x) - 1.f; }
__device__ __forceinline__ float sigm_(float x){ return 1.f/(1.f + __expf(-x)); }

struct EdgePtrs { const int* s_src[3]; const int* s_dst[3]; const int* e_src[3]; const int* e_dst[3]; };

// ---------- CSR build: LDS histogram -> per-block partial counts (no global atomics) ----------
__global__ __launch_bounds__(256)
void k_hist(EdgePtrs ep, int* __restrict__ part) {
  __shared__ int hcnt[NNODE];     // 33 KB
  int g = blockIdx.y, b = blockIdx.x, t = threadIdx.x;
  for (int i = t; i < NNODE; i += 256) hcnt[i] = 0;
  __syncthreads();
  const int* ss_ = ep.s_src[g]; const int* sd_ = ep.s_dst[g];
  const int* es_ = ep.e_src[g]; const int* ed_ = ep.e_dst[g];
  int se0 = b*(ESE/HB);
  for (int i = se0 + t; i < se0 + ESE/HB; i += 256) {
    atomicAdd(&hcnt[ss_[i]], 1);
    atomicAdd(&hcnt[NS + sd_[i]], 1);
  }
  int ek0 = b*(EEK/HB);
  for (int i = ek0 + t; i < ek0 + EEK/HB; i += 256) {
    atomicAdd(&hcnt[NS + es_[i]], 1);
    atomicAdd(&hcnt[NS + NE + ed_[i]], 1);
  }
  __syncthreads();
  int* pp = part + ((size_t)g*HB + b)*NNODE;
  for (int i = t; i < NNODE; i += 256) pp[i] = hcnt[i];
}

// per-graph: row_ptr (prefix over nodes of total counts) + per-block base offsets
__global__ void k_scan(const int* __restrict__ part, int* __restrict__ rp_all,
                       int* __restrict__ boff) {
  __shared__ int sums[1024];
  const int CH = (NNODE + 1023) / 1024;    // 9
  int g = blockIdx.x, t = threadIdx.x;
  const int* pg = part + (size_t)g*HB*NNODE;
  int base = t*CH;
  int local[CH];
  int s = 0;
  for (int j = 0; j < CH; j++) {
    int n = base + j;
    int v = 0;
    if (n < NNODE)
      for (int b = 0; b < HB; b++) v += pg[(size_t)b*NNODE + n];
    local[j] = s; s += v;
  }
  sums[t] = s; __syncthreads();
  for (int off = 1; off < 1024; off <<= 1) {
    int v = (t >= off) ? sums[t - off] : 0;
    __syncthreads();
    sums[t] += v;
    __syncthreads();
  }
  int excl = (t == 0) ? 0 : sums[t - 1];
  int* row_ptr = rp_all + g*RP;
  int* bg = boff + (size_t)g*HB*NNODE;
  for (int j = 0; j < CH; j++) {
    int n = base + j;
    if (n < NNODE) {
      int acc = excl + local[j];
      row_ptr[n] = acc;
      for (int b = 0; b < HB; b++) {
        bg[(size_t)b*NNODE + n] = acc;
        acc += pg[(size_t)b*NNODE + n];
      }
    }
  }
  if (t == 1023) row_ptr[NNODE] = sums[1023];
}

// scatter via LDS cursors initialized from boff (no global atomics)
__global__ __launch_bounds__(256)
void k_scatter(EdgePtrs ep, const int* __restrict__ boff, int* __restrict__ col_all) {
  __shared__ int cur[NNODE];      // 33 KB live cursors
  int g = blockIdx.y, b = blockIdx.x, t = threadIdx.x;
  const int* bg = boff + ((size_t)g*HB + b)*NNODE;
  for (int i = t; i < NNODE; i += 256) cur[i] = bg[i];
  __syncthreads();
  const int* ss_ = ep.s_src[g]; const int* sd_ = ep.s_dst[g];
  const int* es_ = ep.e_src[g]; const int* ed_ = ep.e_dst[g];
  int* col = col_all + (size_t)g*NCSR;
  int se0 = b*(ESE/HB);
  for (int i = se0 + t; i < se0 + ESE/HB; i += 256) {
    int s = ss_[i], d = NS + sd_[i];
    col[atomicAdd(&cur[s], 1)] = d;
    col[atomicAdd(&cur[d], 1)] = s;
  }
  int ek0 = b*(EEK/HB);
  for (int i = ek0 + t; i < ek0 + EEK/HB; i += 256) {
    int s = NS + es_[i], d = NS + NE + ed_[i];
    col[atomicAdd(&cur[s], 1)] = d;
    col[atomicAdd(&cur[d], 1)] = s;
  }
}

// ---------- transpose the 3 head weight matrices ----------
__global__ void k_tr(const float* __restrict__ pW1, const float* __restrict__ pW2,
                     const float* __restrict__ pW3, float* __restrict__ T) {
  __shared__ float tile[32][33];
  int m = blockIdx.z;
  const float* src = m == 0 ? pW1 : (m == 1 ? pW2 : pW3);
  float* dst = T + m*KD*KD;
  int bx = blockIdx.x*32, by = blockIdx.y*32;
  int tx = threadIdx.x, ty = threadIdx.y;   // block (32,8)
  for (int j = 0; j < 32; j += 8)
    tile[ty + j][tx] = src[(by + ty + j)*KD + bx + tx];
  __syncthreads();
  for (int j = 0; j < 32; j += 8)
    dst[(bx + ty + j)*KD + by + tx] = tile[tx][ty + j];
}

// ---------- register-blocked node GEMM ----------
// MODE 0: out = in@Wa (no act) + fused ss/sd (v1=a_s, v2=a_d)
// MODE 3: like MODE 0 but stages rows gathered from embedding tables (g1..g3 = E tables, i1..i3 = ids)
// MODE 1: out = sigm(in@W), W = (blockIdx < grid/2 ? Wa : Wb)   (P|D batched)
// MODE 2: head: stages X = PD[si]-PD[NS+ei] (g1=PD, i1=si, i2=ei);
//         o = sigm(X@Wa + v1[bias]); out[row] = sum(o*v2[row,:])/sum(v2[row,:])
template<int MODE>
__global__ __launch_bounds__(256)
void k_ngemm(const float* __restrict__ in, const float* __restrict__ Wa,
             const float* __restrict__ Wb,
             const float* __restrict__ v1, const float* __restrict__ v2,
             float* __restrict__ out, float* __restrict__ ss, float* __restrict__ sd,
             int nrows,
             const float* __restrict__ g1, const float* __restrict__ g2,
             const float* __restrict__ g3,
             const int* __restrict__ i1, const int* __restrict__ i2,
             const int* __restrict__ i3) {
  __shared__ float ers[32][KD];
  int t = threadIdx.x;
  int row0 = blockIdx.x * 32;
  const float* Wm = (MODE == 1 && blockIdx.x >= (gridDim.x >> 1)) ? Wb : Wa;
  for (int i = t; i < 32*KD; i += 256) {
    int r = i >> 7, k = i & 127;
    int gr = row0 + r;
    float val;
    if (MODE == 3) {
      const float* srow;
      if (gr < NS)           srow = g1 + (size_t)i1[gr]*KD;
      else if (gr < NS + NE) srow = g2 + (size_t)i2[gr - NS]*KD;
      else                   srow = g3 + (size_t)i3[gr - NS - NE]*KD;
      val = srow[k];
    } else if (MODE == 2) {
      val = g1[(size_t)i1[gr]*KD + k] - g1[(size_t)(NS + i2[gr])*KD + k];
    } else {
      val = (gr < nrows) ? in[(size_t)gr*KD + k] : 0.f;
    }
    ers[r][k] = val;
  }
  __syncthreads();
  int w = t >> 6, c = t & 63;
  float acc0[8] = {0,0,0,0,0,0,0,0}, acc1[8] = {0,0,0,0,0,0,0,0};
  #pragma unroll 2
  for (int kc = 0; kc < KD; kc += 4) {
    float wa[4], wb[4];
    #pragma unroll
    for (int j = 0; j < 4; j++) {
      wa[j] = Wm[(kc + j)*KD + c];
      wb[j] = Wm[(kc + j)*KD + c + 64];
    }
    #pragma unroll
    for (int r = 0; r < 8; r++) {
      float4 e = *(const float4*)&ers[w*8 + r][kc];   // wave-uniform broadcast read
      acc0[r] += e.x*wa[0] + e.y*wa[1] + e.z*wa[2] + e.w*wa[3];
      acc1[r] += e.x*wb[0] + e.y*wb[1] + e.z*wb[2] + e.w*wb[3];
    }
  }
  if (MODE == 0 || MODE == 3) {
    float as1 = v1[c], as2 = v1[c + 64], ad1 = v2[c], ad2 = v2[c + 64];
    #pragma unroll
    for (int r = 0; r < 8; r++) {
      int gr = row0 + w*8 + r;
      if (gr < nrows) {
        out[(size_t)gr*KD + c] = acc0[r];
        out[(size_t)gr*KD + c + 64] = acc1[r];
      }
      float s = acc0[r]*as1 + acc1[r]*as2;
      float d = acc0[r]*ad1 + acc1[r]*ad2;
      #pragma unroll
      for (int off = 32; off; off >>= 1) { s += __shfl_xor(s, off); d += __shfl_xor(d, off); }
      if (c == 0 && gr < nrows) { ss[gr] = s; sd[gr] = d; }
    }
  } else if (MODE == 1) {
    #pragma unroll
    for (int r = 0; r < 8; r++) {
      int gr = row0 + w*8 + r;
      if (gr < nrows) {
        out[(size_t)gr*KD + c] = sigm_(acc0[r]);
        out[(size_t)gr*KD + c + 64] = sigm_(acc1[r]);
      }
    }
  } else {
    float b1 = v1[c], b2 = v1[c + 64];
    #pragma unroll
    for (int r = 0; r < 8; r++) {
      int gr = row0 + w*8 + r;
      float kr1 = v2[(size_t)gr*KD + c], kr2 = v2[(size_t)gr*KD + c + 64];
      float o1 = sigm_(acc0[r] + b1), o2 = sigm_(acc1[r] + b2);
      float num = o1*kr1 + o2*kr2, den = kr1 + kr2;
      #pragma unroll
      for (int off = 32; off; off >>= 1) { num += __shfl_xor(num, off); den += __shfl_xor(den, off); }
      if (c == 0) out[gr] = num/den;
    }
  }
}

// ---------- segment-softmax aggregation, 3 graphs batched ----------
// Single-pass (no max subtraction: scores bounded, softmax shift-invariant).
// 4 edge-subgroups x 16 feature-lanes: 8 independent 16B loads in flight/iter.
// Zo == nullptr  => layer 1; Zo != nullptr => layer 2 (skip k rows; g0 -> fp32,
//                  g1/g2 -> fused normalize+bf16 Z only)
__global__ void k_agg(const int* __restrict__ rp_all, const int* __restrict__ col_all,
                      const float* __restrict__ h, const float* __restrict__ ss,
                      const float* __restrict__ sd, float* __restrict__ out,
                      unsigned short* __restrict__ Zo) {
  int gw = blockIdx.x*4 + (threadIdx.x >> 6);
  int lane = threadIdx.x & 63;
  if (gw >= 3*NNODE) return;
  int g = gw / NNODE;
  int node = gw - g*NNODE;
  bool layer2 = (Zo != nullptr);
  if (layer2 && node >= NS + NE) return;        // k rows unused after layer 2
  const int* rp = rp_all + g*RP;
  const int* cl = col_all + (size_t)g*NCSR;
  const float* hg  = layer2 ? h  + (size_t)g*NNODE*KD : h;
  const float* ssg = layer2 ? ss + g*NNODE : ss;
  const float* sdg = layer2 ? sd + g*NNODE : sd;
  int e0 = rp[node], e1 = rp[node + 1];
  float sdv = sdg[node];
  int sub = lane >> 4;       // edge subgroup 0..3
  int fl  = lane & 15;       // feature lane: features fl*8 .. fl*8+7
  float l = 0.f;
  float4 A0 = {0,0,0,0}, A1 = {0,0,0,0};
  for (int base = e0; base < e1; base += 64) {
    int e = base + lane;
    float p = 0.f; int o = 0;
    if (e < e1) { o = cl[e]; p = __expf(lrelu_(ssg[o] + sdv)); }
    l += p;
    int cnt = min(64, e1 - base);
    for (int j = 0; j*4 < cnt; j++) {
      int idx = j*4 + sub;
      float pj = __shfl(p, idx);
      int oj = __shfl(o, idx);
      if (idx < cnt) {
        const float* row = &hg[(size_t)oj*KD + fl*8];
        float4 v0 = *(const float4*)row;
        float4 v1 = *(const float4*)(row + 4);
        A0.x += pj*v0.x; A0.y += pj*v0.y; A0.z += pj*v0.z; A0.w += pj*v0.w;
        A1.x += pj*v1.x; A1.y += pj*v1.y; A1.z += pj*v1.z; A1.w += pj*v1.w;
      }
    }
  }
  #pragma unroll
  for (int off = 32; off; off >>= 1) l += __shfl_xor(l, off);
  #pragma unroll
  for (int off = 16; off <= 32; off <<= 1) {
    A0.x += __shfl_xor(A0.x, off); A0.y += __shfl_xor(A0.y, off);
    A0.z += __shfl_xor(A0.z, off); A0.w += __shfl_xor(A0.w, off);
    A1.x += __shfl_xor(A1.x, off); A1.y += __shfl_xor(A1.y, off);
    A1.z += __shfl_xor(A1.z, off); A1.w += __shfl_xor(A1.w, off);
  }
  float inv = 1.f/(l + 1e-16f);
  float av[8];
  av[0] = elu_(A0.x*inv); av[1] = elu_(A0.y*inv); av[2] = elu_(A0.z*inv); av[3] = elu_(A0.w*inv);
  av[4] = elu_(A1.x*inv); av[5] = elu_(A1.y*inv); av[6] = elu_(A1.z*inv); av[7] = elu_(A1.w*inv);
  if (!layer2 || g == 0) {
    float* orow = &out[(size_t)gw*KD];
    if (sub == 0) *(float4*)&orow[fl*8]     = make_float4(av[0], av[1], av[2], av[3]);
    else if (sub == 1) *(float4*)&orow[fl*8 + 4] = make_float4(av[4], av[5], av[6], av[7]);
  }
  if (layer2 && g >= 1) {
    // fused normalize + bf16 cast
    float nrm = av[0]*av[0] + av[1]*av[1] + av[2]*av[2] + av[3]*av[3]
              + av[4]*av[4] + av[5]*av[5] + av[6]*av[6] + av[7]*av[7];
    #pragma unroll
    for (int off = 1; off <= 8; off <<= 1) nrm += __shfl_xor(nrm, off);
    float invn = 1.f/(sqrtf(nrm) + 1e-12f);
    unsigned short us[8];
    #pragma unroll
    for (int i = 0; i < 8; i++) {
      __hip_bfloat16 b = __float2bfloat16(av[i]*invn);
      us[i] = *(unsigned short*)&b;
    }
    if (sub == 0) {
      unsigned short* zr = Zo + ((size_t)(g - 1)*8192 + node)*KD + fl*8;
      ushort4 u0; u0.x = us[0]; u0.y = us[1]; u0.z = us[2]; u0.w = us[3];
      ushort4 u1; u1.x = us[4]; u1.y = us[5]; u1.z = us[6]; u1.w = us[7];
      *(ushort4*)zr = u0;
      *(ushort4*)(zr + 4) = u1;
    }
  }
}

// ---------- bf16 MFMA similarity GEMM with fused exp/rowsum/colsum/diag ----------
__global__ __launch_bounds__(256)
void k_sim(const unsigned short* __restrict__ Z, float* __restrict__ zbuf,
           float* __restrict__ dg_all) {
  __shared__ unsigned short As[128*KD];   // 32 KB, row r: 16 groups of 8, group g at (g ^ (r&15))
  __shared__ unsigned short Bs[128*KD];   // 32 KB
  int z = blockIdx.z;
  int t = threadIdx.x;
  const unsigned short* Arow = Z + ((size_t)z*NS + (size_t)blockIdx.x*128)*KD;
  const unsigned short* Brow = Z + ((size_t)8192 + (size_t)z*NS + (size_t)blockIdx.y*128)*KD;
  #pragma unroll
  for (int j = 0; j < 8; j++) {
    int G = t + j*256;                     // linear 16B-group id, 0..2047
    int r = G >> 4, g = G & 15;
    int sw = g ^ (r & 15);
    *(float4*)&As[(r*16 + sw)*8] = *(const float4*)&Arow[(size_t)G*8];
    *(float4*)&Bs[(r*16 + sw)*8] = *(const float4*)&Brow[(size_t)G*8];
  }
  __syncthreads();
  int w = t >> 6, lane = t & 63;
  int rw = (w >> 1)*64, cw = (w & 1)*64;
  int m15 = lane & 15, quad = lane >> 4;
  float4_ acc[4][4] = {};
  #pragma unroll
  for (int kq = 0; kq < 4; kq++) {
    short8 a[4], b[4];
    int g = kq*4 + quad;
    #pragma unroll
    for (int mi = 0; mi < 4; mi++) {
      int r = rw + mi*16 + m15;
      a[mi] = *(const short8*)&As[(r*16 + (g ^ (r & 15)))*8];
    }
    #pragma unroll
    for (int ni = 0; ni < 4; ni++) {
      int r = cw + ni*16 + m15;
      b[ni] = *(const short8*)&Bs[(r*16 + (g ^ (r & 15)))*8];
    }
    #pragma unroll
    for (int mi = 0; mi < 4; mi++)
      #pragma unroll
      for (int ni = 0; ni < 4; ni++)
        acc[mi][ni] = __builtin_amdgcn_mfma_f32_16x16x32_bf16(a[mi], b[ni], acc[mi][ni], 0, 0, 0);
  }
  int i0 = blockIdx.x*128, j0 = blockIdx.y*128;
  float* rowsum = zbuf + z*NS;
  float* colsum = zbuf + 2*NS + z*NS;
  float* diag = dg_all + z*NS;
  float cs[4] = {0,0,0,0};
  #pragma unroll
  for (int mi = 0; mi < 4; mi++) {
    float rs[4] = {0,0,0,0};
    #pragma unroll
    for (int ni = 0; ni < 4; ni++) {
      #pragma unroll
      for (int reg = 0; reg < 4; reg++) {
        float sim2 = acc[mi][ni][reg]*2.0f;
        int gi = i0 + rw + mi*16 + quad*4 + reg;     // C/D: row=(lane>>4)*4+reg
        int gj = j0 + cw + ni*16 + m15;              //      col=lane&15
        if (gi == gj) diag[gi] = sim2;
        float e = __expf(sim2);
        rs[reg] += e; cs[ni] += e;
      }
    }
    #pragma unroll
    for (int reg = 0; reg < 4; reg++) {
      float v = rs[reg];
      v += __shfl_xor(v, 1); v += __shfl_xor(v, 2);
      v += __shfl_xor(v, 4); v += __shfl_xor(v, 8);
      if (m15 == 0) atomicAdd(&rowsum[i0 + rw + mi*16 + quad*4 + reg], v);
    }
  }
  #pragma unroll
  for (int ni = 0; ni < 4; ni++) {
    float v = cs[ni];
    v += __shfl_xor(v, 16); v += __shfl_xor(v, 32);
    if (quad == 0) atomicAdd(&colsum[j0 + cw + ni*16 + m15], v);
  }
}

// single block; writes closs directly to out[BQ]
__global__ void k_loss(const float* __restrict__ zbuf, const float* __restrict__ dg_all,
                       float* __restrict__ out) {
  __shared__ float red[256];
  int t = threadIdx.x;
  float v = 0.f;
  for (int z = 0; z < 2; z++)
    for (int i = t; i < NS; i += 256)
      v += logf(zbuf[z*NS + i]) + logf(zbuf[2*NS + z*NS + i]) - 2.f*dg_all[z*NS + i];
  red[t] = v; __syncthreads();
  for (int off = 128; off > 0; off >>= 1) {
    if (t < off) red[t] += red[t + off];
    __syncthreads();
  }
  if (t == 0) out[BQ] = 0.1f*red[0]/(float)NS;
}

extern "C" void kernel_launch(void* const* d_in, const int* in_sizes, int n_in,
                              void* d_out, int out_size, void* d_ws, size_t ws_size,
                              hipStream_t stream) {
  const float* E_stu  = (const float*)d_in[0];
  const float* E_exer = (const float*)d_in[1];
  const float* E_k    = (const float*)d_in[2];
  const float* W1  = (const float*)d_in[3];
  const float* a1s = (const float*)d_in[4];
  const float* a1d = (const float*)d_in[5];
  const float* W2  = (const float*)d_in[6];
  const float* a2s = (const float*)d_in[7];
  const float* a2d = (const float*)d_in[8];
  const float* pW1 = (const float*)d_in[9];
  const float* pW2 = (const float*)d_in[10];
  const float* pW3 = (const float*)d_in[11];
  const float* pb3 = (const float*)d_in[12];
  const float* kn_r = (const float*)d_in[13];
  const int* stu_ids  = (const int*)d_in[14];
  const int* exer_ids = (const int*)d_in[15];
  const int* k_ids    = (const int*)d_in[16];
  EdgePtrs ep;
  for (int g = 0; g < 3; g++) {
    ep.s_src[g] = (const int*)d_in[17 + g*4];
    ep.s_dst[g] = (const int*)d_in[18 + g*4];
    ep.e_src[g] = (const int*)d_in[19 + g*4];
    ep.e_dst[g] = (const int*)d_in[20 + g*4];
  }
  const int* stu_index  = (const int*)d_in[29];
  const int* exer_index = (const int*)d_in[30];
  float* out = (float*)d_out;   // [0..8191] predictions, [8192] closs

  // ---- workspace carve ----
  char* p = (char*)d_ws;
  auto carve = [&](size_t bytes) -> char* {
    char* r = p; p += (bytes + 255) & ~(size_t)255; return r;
  };
  const size_t NODE_F = (size_t)NNODE*KD;
  float* R1 = (float*)carve((3*NODE_F + 6*NNODE)*4);
  float* h0  = R1;                        // layer-1 h (shared across graphs)
  float* ss0 = R1 + NODE_F;
  float* sd0 = ss0 + NNODE;
  float* h3  = R1;                        // layer-2 h x3 (aliases h0, dead by then)
  float* ss3 = R1 + 3*NODE_F;
  float* sd3 = ss3 + 3*NNODE;
  float* Creg = (float*)carve(3*NODE_F*4);   // 12.8 MB, time-multiplexed:
  int*   part = (int*)Creg;                  //   CSR phase: part[3][HB][NNODE] (3.2 MB)
  int*   boff = (int*)Creg + (size_t)3*HB*NNODE;  //           boff[3][HB][NNODE] (3.2 MB)
  float* etmp3 = Creg;                       //   GAT phase: layer-1 agg output x3
  float* PD = Creg;                          //   head phase: P|D (4 MB)
  float* eoutAll = (float*)carve(3*NODE_F*4);
  int* rp_all  = (int*)carve((size_t)3*RP*4);
  int* col_all = (int*)carve((size_t)3*NCSR*4);
  float* pWT = (float*)carve((size_t)3*KD*KD*4);
  float* pW1T = pWT, *pW2T = pWT + KD*KD, *pW3T = pWT + 2*KD*KD;
  float* zbuf = (float*)carve((size_t)4*NS*4);     // rs[2][NS], cs[2][NS]
  float* dg_all = (float*)carve((size_t)2*NS*4);
  unsigned short* Z = (unsigned short*)carve((size_t)2*8192*KD*2);  // bf16 Z1|Z2

  // ---- zero init (ws poisoned 0xAA every launch; only zbuf needs zeros) ----
  hipMemsetAsync(zbuf, 0, (size_t)4*NS*4, stream);

  // ---- CSR build (atomic-free) + weight transpose ----
  k_hist<<<dim3(HB, 3), 256, 0, stream>>>(ep, part);
  k_scan<<<3, 1024, 0, stream>>>(part, rp_all, boff);
  k_scatter<<<dim3(HB, 3), 256, 0, stream>>>(ep, boff, col_all);
  k_tr<<<dim3(4, 4, 3), dim3(32, 8), 0, stream>>>(pW1, pW2, pW3, pWT);

  // ---- GAT layer 1 (h shared across graphs; embedding gather fused) ----
  k_ngemm<3><<<NNODE/32, 256, 0, stream>>>(nullptr, W1, nullptr, a1s, a1d,
                                           h0, ss0, sd0, NNODE,
                                           E_stu, E_exer, E_k, stu_ids, exer_ids, k_ids);
  k_agg<<<3*NNODE/4, 256, 0, stream>>>(rp_all, col_all, h0, ss0, sd0, etmp3, nullptr);

  // ---- GAT layer 2 ----
  k_ngemm<0><<<3*NNODE/32, 256, 0, stream>>>(etmp3, W2, nullptr, a2s, a2d,
                                             h3, ss3, sd3, 3*NNODE,
                                             nullptr, nullptr, nullptr, nullptr, nullptr, nullptr);
  k_agg<<<3*NNODE/4, 256, 0, stream>>>(rp_all, col_all, h3, ss3, sd3, eoutAll, Z);

  // ---- contrastive loss (bf16 MFMA sim) ----
  k_sim<<<dim3(32, 32, 2), 256, 0, stream>>>(Z, zbuf, dg_all);
  k_loss<<<1, 256, 0, stream>>>(zbuf, dg_all, out);

  // ---- prediction head ----
  k_ngemm<1><<<(2*NS)/32, 256, 0, stream>>>(eoutAll, pW1T, pW2T, pb3, kn_r, PD,
                                            nullptr, nullptr, 2*NS,
                                            nullptr, nullptr, nullptr, nullptr, nullptr, nullptr);
  k_ngemm<2><<<BQ/32, 256, 0, stream>>>(nullptr, pW3T, nullptr, pb3, kn_r, out,
                                        nullptr, nullptr, BQ,
                                        PD, nullptr, nullptr, stu_index, exer_index, nullptr);
}

// Round 6
// 366.251 us; speedup vs baseline: 1.4528x; 1.4528x over previous
//
#include <hip/hip_runtime.h>
#include <hip/hip_bf16.h>
#include <math.h>

#define KD 128
#define NS 4096
#define NE 4096
#define NK 128
#define NNODE (NS + NE + NK)      // 8320
#define ESE 131072
#define EEK 16384
#define NCSR (2*ESE + 2*EEK)      // 294912
#define BQ 8192
#define RP (NNODE + 1)
#define HB 32                     // CSR-build blocks per graph

typedef __attribute__((ext_vector_type(8))) short short8;   // 8 bf16 (4 VGPRs)
typedef __attribute__((ext_vector_type(4))) float float4_;  // 4 fp32 acc

__device__ __forceinline__ float lrelu_(float x){ return x >= 0.f ? x : 0.2f*x; }
__device__ __forceinline__ float elu_(float x){ return x > 0.f ? x : __expf(x) - 1.f; }
__device__ __forceinline__ float sigm_(float x){ return 1.f/(1.f + __expf(-x)); }

struct EdgePtrs { const int* s_src[3]; const int* s_dst[3]; const int* e_src[3]; const int* e_dst[3]; };

// ---------- CSR build: LDS histogram -> per-block partial counts (no global atomics) ----------
__global__ __launch_bounds__(256)
void k_hist(EdgePtrs ep, int* __restrict__ part) {
  __shared__ int hcnt[NNODE];     // 33 KB
  int g = blockIdx.y, b = blockIdx.x, t = threadIdx.x;
  for (int i = t; i < NNODE; i += 256) hcnt[i] = 0;
  __syncthreads();
  const int* ss_ = ep.s_src[g]; const int* sd_ = ep.s_dst[g];
  const int* es_ = ep.e_src[g]; const int* ed_ = ep.e_dst[g];
  int se0 = b*(ESE/HB);
  for (int i = se0 + t; i < se0 + ESE/HB; i += 256) {
    atomicAdd(&hcnt[ss_[i]], 1);
    atomicAdd(&hcnt[NS + sd_[i]], 1);
  }
  int ek0 = b*(EEK/HB);
  for (int i = ek0 + t; i < ek0 + EEK/HB; i += 256) {
    atomicAdd(&hcnt[NS + es_[i]], 1);
    atomicAdd(&hcnt[NS + NE + ed_[i]], 1);
  }
  __syncthreads();
  int* pp = part + ((size_t)g*HB + b)*NNODE;
  for (int i = t; i < NNODE; i += 256) pp[i] = hcnt[i];
}

// thread-per-node partial-sum: cnt[g][n] = sum_b part[g][b][n]  (coalesced over n)
__global__ void k_sumpart(const int* __restrict__ part, int* __restrict__ cnt_all) {
  int idx = blockIdx.x*256 + threadIdx.x;
  if (idx >= 3*NNODE) return;
  int g = idx / NNODE, n = idx - g*NNODE;
  const int* pg = part + (size_t)g*HB*NNODE + n;
  int s = 0;
  #pragma unroll
  for (int b = 0; b < HB; b++) s += pg[(size_t)b*NNODE];
  cnt_all[idx] = s;
}

// per-graph single-block scan of cnt -> row_ptr (lightweight: 9 reads/thread)
__global__ void k_scan(const int* __restrict__ cnt_all, int* __restrict__ rp_all) {
  __shared__ int sums[1024];
  const int CH = (NNODE + 1023) / 1024;    // 9
  int g = blockIdx.x, t = threadIdx.x;
  const int* cnt = cnt_all + g*NNODE;
  int* row_ptr = rp_all + g*RP;
  int base = t*CH;
  int local[CH];
  int s = 0;
  for (int j = 0; j < CH; j++) {
    int v = (base + j < NNODE) ? cnt[base + j] : 0;
    local[j] = s; s += v;
  }
  sums[t] = s; __syncthreads();
  for (int off = 1; off < 1024; off <<= 1) {
    int v = (t >= off) ? sums[t - off] : 0;
    __syncthreads();
    sums[t] += v;
    __syncthreads();
  }
  int excl = (t == 0) ? 0 : sums[t - 1];
  for (int j = 0; j < CH; j++)
    if (base + j < NNODE) row_ptr[base + j] = excl + local[j];
  if (t == 1023) row_ptr[NNODE] = sums[1023];
}

// thread-per-node: emit per-block cursors boff[g][b][n] (coalesced over n)
__global__ void k_boff(const int* __restrict__ part, const int* __restrict__ rp_all,
                       int* __restrict__ boff) {
  int idx = blockIdx.x*256 + threadIdx.x;
  if (idx >= 3*NNODE) return;
  int g = idx / NNODE, n = idx - g*NNODE;
  const int* pg = part + (size_t)g*HB*NNODE + n;
  int* bg = boff + (size_t)g*HB*NNODE + n;
  int acc = rp_all[g*RP + n];
  #pragma unroll
  for (int b = 0; b < HB; b++) {
    bg[(size_t)b*NNODE] = acc;
    acc += pg[(size_t)b*NNODE];
  }
}

// scatter via LDS cursors initialized from boff (no global atomics)
__global__ __launch_bounds__(256)
void k_scatter(EdgePtrs ep, const int* __restrict__ boff, int* __restrict__ col_all) {
  __shared__ int cur[NNODE];      // 33 KB live cursors
  int g = blockIdx.y, b = blockIdx.x, t = threadIdx.x;
  const int* bg = boff + ((size_t)g*HB + b)*NNODE;
  for (int i = t; i < NNODE; i += 256) cur[i] = bg[i];
  __syncthreads();
  const int* ss_ = ep.s_src[g]; const int* sd_ = ep.s_dst[g];
  const int* es_ = ep.e_src[g]; const int* ed_ = ep.e_dst[g];
  int* col = col_all + (size_t)g*NCSR;
  int se0 = b*(ESE/HB);
  for (int i = se0 + t; i < se0 + ESE/HB; i += 256) {
    int s = ss_[i], d = NS + sd_[i];
    col[atomicAdd(&cur[s], 1)] = d;
    col[atomicAdd(&cur[d], 1)] = s;
  }
  int ek0 = b*(EEK/HB);
  for (int i = ek0 + t; i < ek0 + EEK/HB; i += 256) {
    int s = NS + es_[i], d = NS + NE + ed_[i];
    col[atomicAdd(&cur[s], 1)] = d;
    col[atomicAdd(&cur[d], 1)] = s;
  }
}

// ---------- transpose the 3 head weight matrices ----------
__global__ void k_tr(const float* __restrict__ pW1, const float* __restrict__ pW2,
                     const float* __restrict__ pW3, float* __restrict__ T) {
  __shared__ float tile[32][33];
  int m = blockIdx.z;
  const float* src = m == 0 ? pW1 : (m == 1 ? pW2 : pW3);
  float* dst = T + m*KD*KD;
  int bx = blockIdx.x*32, by = blockIdx.y*32;
  int tx = threadIdx.x, ty = threadIdx.y;   // block (32,8)
  for (int j = 0; j < 32; j += 8)
    tile[ty + j][tx] = src[(by + ty + j)*KD + bx + tx];
  __syncthreads();
  for (int j = 0; j < 32; j += 8)
    dst[(bx + ty + j)*KD + by + tx] = tile[tx][ty + j];
}

// ---------- register-blocked node GEMM ----------
// MODE 0: out = in@Wa (no act) + fused ss/sd (v1=a_s, v2=a_d)
// MODE 3: like MODE 0 but stages rows gathered from embedding tables (g1..g3 = E tables, i1..i3 = ids)
// MODE 1: out = sigm(in@W), W = (blockIdx < grid/2 ? Wa : Wb)   (P|D batched)
// MODE 2: head: stages X = PD[si]-PD[NS+ei] (g1=PD, i1=si, i2=ei);
//         o = sigm(X@Wa + v1[bias]); out[row] = sum(o*v2[row,:])/sum(v2[row,:])
template<int MODE>
__global__ __launch_bounds__(256)
void k_ngemm(const float* __restrict__ in, const float* __restrict__ Wa,
             const float* __restrict__ Wb,
             const float* __restrict__ v1, const float* __restrict__ v2,
             float* __restrict__ out, float* __restrict__ ss, float* __restrict__ sd,
             int nrows,
             const float* __restrict__ g1, const float* __restrict__ g2,
             const float* __restrict__ g3,
             const int* __restrict__ i1, const int* __restrict__ i2,
             const int* __restrict__ i3) {
  __shared__ float ers[32][KD];
  int t = threadIdx.x;
  int row0 = blockIdx.x * 32;
  const float* Wm = (MODE == 1 && blockIdx.x >= (gridDim.x >> 1)) ? Wb : Wa;
  for (int i = t; i < 32*KD; i += 256) {
    int r = i >> 7, k = i & 127;
    int gr = row0 + r;
    float val;
    if (MODE == 3) {
      const float* srow;
      if (gr < NS)           srow = g1 + (size_t)i1[gr]*KD;
      else if (gr < NS + NE) srow = g2 + (size_t)i2[gr - NS]*KD;
      else                   srow = g3 + (size_t)i3[gr - NS - NE]*KD;
      val = srow[k];
    } else if (MODE == 2) {
      val = g1[(size_t)i1[gr]*KD + k] - g1[(size_t)(NS + i2[gr])*KD + k];
    } else {
      val = (gr < nrows) ? in[(size_t)gr*KD + k] : 0.f;
    }
    ers[r][k] = val;
  }
  __syncthreads();
  int w = t >> 6, c = t & 63;
  float acc0[8] = {0,0,0,0,0,0,0,0}, acc1[8] = {0,0,0,0,0,0,0,0};
  #pragma unroll 2
  for (int kc = 0; kc < KD; kc += 4) {
    float wa[4], wb[4];
    #pragma unroll
    for (int j = 0; j < 4; j++) {
      wa[j] = Wm[(kc + j)*KD + c];
      wb[j] = Wm[(kc + j)*KD + c + 64];
    }
    #pragma unroll
    for (int r = 0; r < 8; r++) {
      float4 e = *(const float4*)&ers[w*8 + r][kc];   // wave-uniform broadcast read
      acc0[r] += e.x*wa[0] + e.y*wa[1] + e.z*wa[2] + e.w*wa[3];
      acc1[r] += e.x*wb[0] + e.y*wb[1] + e.z*wb[2] + e.w*wb[3];
    }
  }
  if (MODE == 0 || MODE == 3) {
    float as1 = v1[c], as2 = v1[c + 64], ad1 = v2[c], ad2 = v2[c + 64];
    #pragma unroll
    for (int r = 0; r < 8; r++) {
      int gr = row0 + w*8 + r;
      if (gr < nrows) {
        out[(size_t)gr*KD + c] = acc0[r];
        out[(size_t)gr*KD + c + 64] = acc1[r];
      }
      float s = acc0[r]*as1 + acc1[r]*as2;
      float d = acc0[r]*ad1 + acc1[r]*ad2;
      #pragma unroll
      for (int off = 32; off; off >>= 1) { s += __shfl_xor(s, off); d += __shfl_xor(d, off); }
      if (c == 0 && gr < nrows) { ss[gr] = s; sd[gr] = d; }
    }
  } else if (MODE == 1) {
    #pragma unroll
    for (int r = 0; r < 8; r++) {
      int gr = row0 + w*8 + r;
      if (gr < nrows) {
        out[(size_t)gr*KD + c] = sigm_(acc0[r]);
        out[(size_t)gr*KD + c + 64] = sigm_(acc1[r]);
      }
    }
  } else {
    float b1 = v1[c], b2 = v1[c + 64];
    #pragma unroll
    for (int r = 0; r < 8; r++) {
      int gr = row0 + w*8 + r;
      float kr1 = v2[(size_t)gr*KD + c], kr2 = v2[(size_t)gr*KD + c + 64];
      float o1 = sigm_(acc0[r] + b1), o2 = sigm_(acc1[r] + b2);
      float num = o1*kr1 + o2*kr2, den = kr1 + kr2;
      #pragma unroll
      for (int off = 32; off; off >>= 1) { num += __shfl_xor(num, off); den += __shfl_xor(den, off); }
      if (c == 0) out[gr] = num/den;
    }
  }
}

// ---------- segment-softmax aggregation, 3 graphs batched ----------
// Single-pass (no max subtraction: scores bounded, softmax shift-invariant).
// 4 edge-subgroups x 16 feature-lanes: 8 independent 16B loads in flight/iter.
// Zo == nullptr  => layer 1; Zo != nullptr => layer 2 (skip k rows; g0 -> fp32,
//                  g1/g2 -> fused normalize+bf16 Z only)
__global__ void k_agg(const int* __restrict__ rp_all, const int* __restrict__ col_all,
                      const float* __restrict__ h, const float* __restrict__ ss,
                      const float* __restrict__ sd, float* __restrict__ out,
                      unsigned short* __restrict__ Zo) {
  int gw = blockIdx.x*4 + (threadIdx.x >> 6);
  int lane = threadIdx.x & 63;
  if (gw >= 3*NNODE) return;
  int g = gw / NNODE;
  int node = gw - g*NNODE;
  bool layer2 = (Zo != nullptr);
  if (layer2 && node >= NS + NE) return;        // k rows unused after layer 2
  const int* rp = rp_all + g*RP;
  const int* cl = col_all + (size_t)g*NCSR;
  const float* hg  = layer2 ? h  + (size_t)g*NNODE*KD : h;
  const float* ssg = layer2 ? ss + g*NNODE : ss;
  const float* sdg = layer2 ? sd + g*NNODE : sd;
  int e0 = rp[node], e1 = rp[node + 1];
  float sdv = sdg[node];
  int sub = lane >> 4;       // edge subgroup 0..3
  int fl  = lane & 15;       // feature lane: features fl*8 .. fl*8+7
  float l = 0.f;
  float4 A0 = {0,0,0,0}, A1 = {0,0,0,0};
  for (int base = e0; base < e1; base += 64) {
    int e = base + lane;
    float p = 0.f; int o = 0;
    if (e < e1) { o = cl[e]; p = __expf(lrelu_(ssg[o] + sdv)); }
    l += p;
    int cnt = min(64, e1 - base);
    for (int j = 0; j*4 < cnt; j++) {
      int idx = j*4 + sub;
      float pj = __shfl(p, idx);
      int oj = __shfl(o, idx);
      if (idx < cnt) {
        const float* row = &hg[(size_t)oj*KD + fl*8];
        float4 v0 = *(const float4*)row;
        float4 v1 = *(const float4*)(row + 4);
        A0.x += pj*v0.x; A0.y += pj*v0.y; A0.z += pj*v0.z; A0.w += pj*v0.w;
        A1.x += pj*v1.x; A1.y += pj*v1.y; A1.z += pj*v1.z; A1.w += pj*v1.w;
      }
    }
  }
  #pragma unroll
  for (int off = 32; off; off >>= 1) l += __shfl_xor(l, off);
  #pragma unroll
  for (int off = 16; off <= 32; off <<= 1) {
    A0.x += __shfl_xor(A0.x, off); A0.y += __shfl_xor(A0.y, off);
    A0.z += __shfl_xor(A0.z, off); A0.w += __shfl_xor(A0.w, off);
    A1.x += __shfl_xor(A1.x, off); A1.y += __shfl_xor(A1.y, off);
    A1.z += __shfl_xor(A1.z, off); A1.w += __shfl_xor(A1.w, off);
  }
  float inv = 1.f/(l + 1e-16f);
  float av[8];
  av[0] = elu_(A0.x*inv); av[1] = elu_(A0.y*inv); av[2] = elu_(A0.z*inv); av[3] = elu_(A0.w*inv);
  av[4] = elu_(A1.x*inv); av[5] = elu_(A1.y*inv); av[6] = elu_(A1.z*inv); av[7] = elu_(A1.w*inv);
  if (!layer2 || g == 0) {
    float* orow = &out[(size_t)gw*KD];
    if (sub == 0) *(float4*)&orow[fl*8]     = make_float4(av[0], av[1], av[2], av[3]);
    else if (sub == 1) *(float4*)&orow[fl*8 + 4] = make_float4(av[4], av[5], av[6], av[7]);
  }
  if (layer2 && g >= 1) {
    // fused normalize + bf16 cast
    float nrm = av[0]*av[0] + av[1]*av[1] + av[2]*av[2] + av[3]*av[3]
              + av[4]*av[4] + av[5]*av[5] + av[6]*av[6] + av[7]*av[7];
    #pragma unroll
    for (int off = 1; off <= 8; off <<= 1) nrm += __shfl_xor(nrm, off);
    float invn = 1.f/(sqrtf(nrm) + 1e-12f);
    unsigned short us[8];
    #pragma unroll
    for (int i = 0; i < 8; i++) {
      __hip_bfloat16 b = __float2bfloat16(av[i]*invn);
      us[i] = *(unsigned short*)&b;
    }
    if (sub == 0) {
      unsigned short* zr = Zo + ((size_t)(g - 1)*8192 + node)*KD + fl*8;
      ushort4 u0; u0.x = us[0]; u0.y = us[1]; u0.z = us[2]; u0.w = us[3];
      ushort4 u1; u1.x = us[4]; u1.y = us[5]; u1.z = us[6]; u1.w = us[7];
      *(ushort4*)zr = u0;
      *(ushort4*)(zr + 4) = u1;
    }
  }
}

// ---------- bf16 MFMA similarity GEMM with fused exp/rowsum/colsum/diag ----------
__global__ __launch_bounds__(256)
void k_sim(const unsigned short* __restrict__ Z, float* __restrict__ zbuf,
           float* __restrict__ dg_all) {
  __shared__ unsigned short As[128*KD];   // 32 KB, row r: 16 groups of 8, group g at (g ^ (r&15))
  __shared__ unsigned short Bs[128*KD];   // 32 KB
  int z = blockIdx.z;
  int t = threadIdx.x;
  const unsigned short* Arow = Z + ((size_t)z*NS + (size_t)blockIdx.x*128)*KD;
  const unsigned short* Brow = Z + ((size_t)8192 + (size_t)z*NS + (size_t)blockIdx.y*128)*KD;
  #pragma unroll
  for (int j = 0; j < 8; j++) {
    int G = t + j*256;                     // linear 16B-group id, 0..2047
    int r = G >> 4, g = G & 15;
    int sw = g ^ (r & 15);
    *(float4*)&As[(r*16 + sw)*8] = *(const float4*)&Arow[(size_t)G*8];
    *(float4*)&Bs[(r*16 + sw)*8] = *(const float4*)&Brow[(size_t)G*8];
  }
  __syncthreads();
  int w = t >> 6, lane = t & 63;
  int rw = (w >> 1)*64, cw = (w & 1)*64;
  int m15 = lane & 15, quad = lane >> 4;
  float4_ acc[4][4] = {};
  #pragma unroll
  for (int kq = 0; kq < 4; kq++) {
    short8 a[4], b[4];
    int g = kq*4 + quad;
    #pragma unroll
    for (int mi = 0; mi < 4; mi++) {
      int r = rw + mi*16 + m15;
      a[mi] = *(const short8*)&As[(r*16 + (g ^ (r & 15)))*8];
    }
    #pragma unroll
    for (int ni = 0; ni < 4; ni++) {
      int r = cw + ni*16 + m15;
      b[ni] = *(const short8*)&Bs[(r*16 + (g ^ (r & 15)))*8];
    }
    #pragma unroll
    for (int mi = 0; mi < 4; mi++)
      #pragma unroll
      for (int ni = 0; ni < 4; ni++)
        acc[mi][ni] = __builtin_amdgcn_mfma_f32_16x16x32_bf16(a[mi], b[ni], acc[mi][ni], 0, 0, 0);
  }
  int i0 = blockIdx.x*128, j0 = blockIdx.y*128;
  float* rowsum = zbuf + z*NS;
  float* colsum = zbuf + 2*NS + z*NS;
  float* diag = dg_all + z*NS;
  float cs[4] = {0,0,0,0};
  #pragma unroll
  for (int mi = 0; mi < 4; mi++) {
    float rs[4] = {0,0,0,0};
    #pragma unroll
    for (int ni = 0; ni < 4; ni++) {
      #pragma unroll
      for (int reg = 0; reg < 4; reg++) {
        float sim2 = acc[mi][ni][reg]*2.0f;
        int gi = i0 + rw + mi*16 + quad*4 + reg;     // C/D: row=(lane>>4)*4+reg
        int gj = j0 + cw + ni*16 + m15;              //      col=lane&15
        if (gi == gj) diag[gi] = sim2;
        float e = __expf(sim2);
        rs[reg] += e; cs[ni] += e;
      }
    }
    #pragma unroll
    for (int reg = 0; reg < 4; reg++) {
      float v = rs[reg];
      v += __shfl_xor(v, 1); v += __shfl_xor(v, 2);
      v += __shfl_xor(v, 4); v += __shfl_xor(v, 8);
      if (m15 == 0) atomicAdd(&rowsum[i0 + rw + mi*16 + quad*4 + reg], v);
    }
  }
  #pragma unroll
  for (int ni = 0; ni < 4; ni++) {
    float v = cs[ni];
    v += __shfl_xor(v, 16); v += __shfl_xor(v, 32);
    if (quad == 0) atomicAdd(&colsum[j0 + cw + ni*16 + m15], v);
  }
}

// single block; writes closs directly to out[BQ]
__global__ void k_loss(const float* __restrict__ zbuf, const float* __restrict__ dg_all,
                       float* __restrict__ out) {
  __shared__ float red[256];
  int t = threadIdx.x;
  float v = 0.f;
  for (int z = 0; z < 2; z++)
    for (int i = t; i < NS; i += 256)
      v += logf(zbuf[z*NS + i]) + logf(zbuf[2*NS + z*NS + i]) - 2.f*dg_all[z*NS + i];
  red[t] = v; __syncthreads();
  for (int off = 128; off > 0; off >>= 1) {
    if (t < off) red[t] += red[t + off];
    __syncthreads();
  }
  if (t == 0) out[BQ] = 0.1f*red[0]/(float)NS;
}

extern "C" void kernel_launch(void* const* d_in, const int* in_sizes, int n_in,
                              void* d_out, int out_size, void* d_ws, size_t ws_size,
                              hipStream_t stream) {
  const float* E_stu  = (const float*)d_in[0];
  const float* E_exer = (const float*)d_in[1];
  const float* E_k    = (const float*)d_in[2];
  const float* W1  = (const float*)d_in[3];
  const float* a1s = (const float*)d_in[4];
  const float* a1d = (const float*)d_in[5];
  const float* W2  = (const float*)d_in[6];
  const float* a2s = (const float*)d_in[7];
  const float* a2d = (const float*)d_in[8];
  const float* pW1 = (const float*)d_in[9];
  const float* pW2 = (const float*)d_in[10];
  const float* pW3 = (const float*)d_in[11];
  const float* pb3 = (const float*)d_in[12];
  const float* kn_r = (const float*)d_in[13];
  const int* stu_ids  = (const int*)d_in[14];
  const int* exer_ids = (const int*)d_in[15];
  const int* k_ids    = (const int*)d_in[16];
  EdgePtrs ep;
  for (int g = 0; g < 3; g++) {
    ep.s_src[g] = (const int*)d_in[17 + g*4];
    ep.s_dst[g] = (const int*)d_in[18 + g*4];
    ep.e_src[g] = (const int*)d_in[19 + g*4];
    ep.e_dst[g] = (const int*)d_in[20 + g*4];
  }
  const int* stu_index  = (const int*)d_in[29];
  const int* exer_index = (const int*)d_in[30];
  float* out = (float*)d_out;   // [0..8191] predictions, [8192] closs

  // ---- workspace carve ----
  char* p = (char*)d_ws;
  auto carve = [&](size_t bytes) -> char* {
    char* r = p; p += (bytes + 255) & ~(size_t)255; return r;
  };
  const size_t NODE_F = (size_t)NNODE*KD;
  float* R1 = (float*)carve((3*NODE_F + 6*NNODE)*4);
  float* h0  = R1;                        // layer-1 h (shared across graphs)
  float* ss0 = R1 + NODE_F;
  float* sd0 = ss0 + NNODE;
  float* h3  = R1;                        // layer-2 h x3 (aliases h0, dead by then)
  float* ss3 = R1 + 3*NODE_F;
  float* sd3 = ss3 + 3*NNODE;
  float* Creg = (float*)carve(3*NODE_F*4);   // 12.8 MB, time-multiplexed:
  int*   part = (int*)Creg;                  //   CSR phase: part[3][HB][NNODE] (3.2 MB)
  int*   boff = (int*)Creg + (size_t)3*HB*NNODE;  //           boff[3][HB][NNODE] (3.2 MB)
  float* etmp3 = Creg;                       //   GAT phase: layer-1 agg output x3
  float* PD = Creg;                          //   head phase: P|D (4 MB)
  float* eoutAll = (float*)carve(3*NODE_F*4);
  int* cnt_all = (int*)carve((size_t)3*NNODE*4);
  int* rp_all  = (int*)carve((size_t)3*RP*4);
  int* col_all = (int*)carve((size_t)3*NCSR*4);
  float* pWT = (float*)carve((size_t)3*KD*KD*4);
  float* pW1T = pWT, *pW2T = pWT + KD*KD, *pW3T = pWT + 2*KD*KD;
  float* zbuf = (float*)carve((size_t)4*NS*4);     // rs[2][NS], cs[2][NS]
  float* dg_all = (float*)carve((size_t)2*NS*4);
  unsigned short* Z = (unsigned short*)carve((size_t)2*8192*KD*2);  // bf16 Z1|Z2

  // ---- zero init (ws poisoned 0xAA every launch; only zbuf needs zeros) ----
  hipMemsetAsync(zbuf, 0, (size_t)4*NS*4, stream);

  // ---- CSR build (atomic-free, all stages parallel) + weight transpose ----
  k_hist<<<dim3(HB, 3), 256, 0, stream>>>(ep, part);
  k_sumpart<<<(3*NNODE + 255)/256, 256, 0, stream>>>(part, cnt_all);
  k_scan<<<3, 1024, 0, stream>>>(cnt_all, rp_all);
  k_boff<<<(3*NNODE + 255)/256, 256, 0, stream>>>(part, rp_all, boff);
  k_scatter<<<dim3(HB, 3), 256, 0, stream>>>(ep, boff, col_all);
  k_tr<<<dim3(4, 4, 3), dim3(32, 8), 0, stream>>>(pW1, pW2, pW3, pWT);

  // ---- GAT layer 1 (h shared across graphs; embedding gather fused) ----
  k_ngemm<3><<<NNODE/32, 256, 0, stream>>>(nullptr, W1, nullptr, a1s, a1d,
                                           h0, ss0, sd0, NNODE,
                                           E_stu, E_exer, E_k, stu_ids, exer_ids, k_ids);
  k_agg<<<3*NNODE/4, 256, 0, stream>>>(rp_all, col_all, h0, ss0, sd0, etmp3, nullptr);

  // ---- GAT layer 2 ----
  k_ngemm<0><<<3*NNODE/32, 256, 0, stream>>>(etmp3, W2, nullptr, a2s, a2d,
                                             h3, ss3, sd3, 3*NNODE,
                                             nullptr, nullptr, nullptr, nullptr, nullptr, nullptr);
  k_agg<<<3*NNODE/4, 256, 0, stream>>>(rp_all, col_all, h3, ss3, sd3, eoutAll, Z);

  // ---- contrastive loss (bf16 MFMA sim) ----
  k_sim<<<dim3(32, 32, 2), 256, 0, stream>>>(Z, zbuf, dg_all);
  k_loss<<<1, 256, 0, stream>>>(zbuf, dg_all, out);

  // ---- prediction head ----
  k_ngemm<1><<<(2*NS)/32, 256, 0, stream>>>(eoutAll, pW1T, pW2T, pb3, kn_r, PD,
                                            nullptr, nullptr, 2*NS,
                                            nullptr, nullptr, nullptr, nullptr, nullptr, nullptr);
  k_ngemm<2><<<BQ/32, 256, 0, stream>>>(nullptr, pW3T, nullptr, pb3, kn_r, out,
                                        nullptr, nullptr, BQ,
                                        PD, nullptr, nullptr, stu_index, exer_index, nullptr);
}

// Round 7
// 346.648 us; speedup vs baseline: 1.5349x; 1.0566x over previous
//
#include <hip/hip_runtime.h>
#include <hip/hip_bf16.h>
#include <math.h>

#define KD 128
#define NS 4096
#define NE 4096
#define NK 128
#define NNODE (NS + NE + NK)      // 8320
#define ESE 131072
#define EEK 16384
#define NCSR (2*ESE + 2*EEK)      // 294912
#define BQ 8192
#define RP (NNODE + 1)
#define HB 32                     // CSR-build blocks per graph

typedef __attribute__((ext_vector_type(8))) short short8;   // 8 bf16 (4 VGPRs)
typedef __attribute__((ext_vector_type(4))) float float4_;  // 4 fp32 acc

__device__ __forceinline__ float lrelu_(float x){ return x >= 0.f ? x : 0.2f*x; }
__device__ __forceinline__ float elu_(float x){ return x > 0.f ? x : __expf(x) - 1.f; }
__device__ __forceinline__ float sigm_(float x){ return 1.f/(1.f + __expf(-x)); }
__device__ __forceinline__ float bf2f_(unsigned short u){
  union { unsigned int i; float f; } v; v.i = ((unsigned int)u) << 16; return v.f;
}
__device__ __forceinline__ unsigned short f2b_(float x){
  __hip_bfloat16 b = __float2bfloat16(x); return *(unsigned short*)&b;
}

struct EdgePtrs { const int* s_src[3]; const int* s_dst[3]; const int* e_src[3]; const int* e_dst[3]; };

// ---------- CSR build: LDS histogram -> per-block partial counts (no global atomics) ----------
__global__ __launch_bounds__(256)
void k_hist(EdgePtrs ep, int* __restrict__ part) {
  __shared__ int hcnt[NNODE];     // 33 KB
  int g = blockIdx.y, b = blockIdx.x, t = threadIdx.x;
  for (int i = t; i < NNODE; i += 256) hcnt[i] = 0;
  __syncthreads();
  const int* ss_ = ep.s_src[g]; const int* sd_ = ep.s_dst[g];
  const int* es_ = ep.e_src[g]; const int* ed_ = ep.e_dst[g];
  int se0 = b*(ESE/HB);
  for (int i = se0 + t; i < se0 + ESE/HB; i += 256) {
    atomicAdd(&hcnt[ss_[i]], 1);
    atomicAdd(&hcnt[NS + sd_[i]], 1);
  }
  int ek0 = b*(EEK/HB);
  for (int i = ek0 + t; i < ek0 + EEK/HB; i += 256) {
    atomicAdd(&hcnt[NS + es_[i]], 1);
    atomicAdd(&hcnt[NS + NE + ed_[i]], 1);
  }
  __syncthreads();
  int* pp = part + ((size_t)g*HB + b)*NNODE;
  for (int i = t; i < NNODE; i += 256) pp[i] = hcnt[i];
}

// thread-per-node partial-sum: cnt[g][n] = sum_b part[g][b][n]  (coalesced over n)
__global__ void k_sumpart(const int* __restrict__ part, int* __restrict__ cnt_all) {
  int idx = blockIdx.x*256 + threadIdx.x;
  if (idx >= 3*NNODE) return;
  int g = idx / NNODE, n = idx - g*NNODE;
  const int* pg = part + (size_t)g*HB*NNODE + n;
  int s = 0;
  #pragma unroll
  for (int b = 0; b < HB; b++) s += pg[(size_t)b*NNODE];
  cnt_all[idx] = s;
}

// per-graph single-block scan of cnt -> row_ptr (lightweight: 9 reads/thread)
__global__ void k_scan(const int* __restrict__ cnt_all, int* __restrict__ rp_all) {
  __shared__ int sums[1024];
  const int CH = (NNODE + 1023) / 1024;    // 9
  int g = blockIdx.x, t = threadIdx.x;
  const int* cnt = cnt_all + g*NNODE;
  int* row_ptr = rp_all + g*RP;
  int base = t*CH;
  int local[CH];
  int s = 0;
  for (int j = 0; j < CH; j++) {
    int v = (base + j < NNODE) ? cnt[base + j] : 0;
    local[j] = s; s += v;
  }
  sums[t] = s; __syncthreads();
  for (int off = 1; off < 1024; off <<= 1) {
    int v = (t >= off) ? sums[t - off] : 0;
    __syncthreads();
    sums[t] += v;
    __syncthreads();
  }
  int excl = (t == 0) ? 0 : sums[t - 1];
  for (int j = 0; j < CH; j++)
    if (base + j < NNODE) row_ptr[base + j] = excl + local[j];
  if (t == 1023) row_ptr[NNODE] = sums[1023];
}

// thread-per-node: emit per-block cursors boff[g][b][n] (coalesced over n)
__global__ void k_boff(const int* __restrict__ part, const int* __restrict__ rp_all,
                       int* __restrict__ boff) {
  int idx = blockIdx.x*256 + threadIdx.x;
  if (idx >= 3*NNODE) return;
  int g = idx / NNODE, n = idx - g*NNODE;
  const int* pg = part + (size_t)g*HB*NNODE + n;
  int* bg = boff + (size_t)g*HB*NNODE + n;
  int acc = rp_all[g*RP + n];
  #pragma unroll
  for (int b = 0; b < HB; b++) {
    bg[(size_t)b*NNODE] = acc;
    acc += pg[(size_t)b*NNODE];
  }
}

// scatter via LDS cursors initialized from boff (no global atomics); col stored ushort
__global__ __launch_bounds__(256)
void k_scatter(EdgePtrs ep, const int* __restrict__ boff, unsigned short* __restrict__ col_all) {
  __shared__ int cur[NNODE];      // 33 KB live cursors
  int g = blockIdx.y, b = blockIdx.x, t = threadIdx.x;
  const int* bg = boff + ((size_t)g*HB + b)*NNODE;
  for (int i = t; i < NNODE; i += 256) cur[i] = bg[i];
  __syncthreads();
  const int* ss_ = ep.s_src[g]; const int* sd_ = ep.s_dst[g];
  const int* es_ = ep.e_src[g]; const int* ed_ = ep.e_dst[g];
  unsigned short* col = col_all + (size_t)g*NCSR;
  int se0 = b*(ESE/HB);
  for (int i = se0 + t; i < se0 + ESE/HB; i += 256) {
    int s = ss_[i], d = NS + sd_[i];
    col[atomicAdd(&cur[s], 1)] = (unsigned short)d;
    col[atomicAdd(&cur[d], 1)] = (unsigned short)s;
  }
  int ek0 = b*(EEK/HB);
  for (int i = ek0 + t; i < ek0 + EEK/HB; i += 256) {
    int s = NS + es_[i], d = NS + NE + ed_[i];
    col[atomicAdd(&cur[s], 1)] = (unsigned short)d;
    col[atomicAdd(&cur[d], 1)] = (unsigned short)s;
  }
}

// ---------- transpose the 3 head weight matrices ----------
__global__ void k_tr(const float* __restrict__ pW1, const float* __restrict__ pW2,
                     const float* __restrict__ pW3, float* __restrict__ T) {
  __shared__ float tile[32][33];
  int m = blockIdx.z;
  const float* src = m == 0 ? pW1 : (m == 1 ? pW2 : pW3);
  float* dst = T + m*KD*KD;
  int bx = blockIdx.x*32, by = blockIdx.y*32;
  int tx = threadIdx.x, ty = threadIdx.y;   // block (32,8)
  for (int j = 0; j < 32; j += 8)
    tile[ty + j][tx] = src[(by + ty + j)*KD + bx + tx];
  __syncthreads();
  for (int j = 0; j < 32; j += 8)
    dst[(bx + ty + j)*KD + by + tx] = tile[tx][ty + j];
}

// ---------- register-blocked node GEMM ----------
// MODE 0: hb = bf16(in@Wa) + fused ss/sd (v1=a_s, v2=a_d); no fp32 h output
// MODE 3: like MODE 0 but stages rows gathered from embedding tables
// MODE 1: out = sigm(in@W), W = (blockIdx < grid/2 ? Wa : Wb)   (P|D batched)
// MODE 2: head: stages X = PD[si]-PD[NS+ei]; o = sigm(X@Wa + v1);
//         out[row] = sum(o*v2[row,:])/sum(v2[row,:])
template<int MODE>
__global__ __launch_bounds__(256)
void k_ngemm(const float* __restrict__ in, const float* __restrict__ Wa,
             const float* __restrict__ Wb,
             const float* __restrict__ v1, const float* __restrict__ v2,
             float* __restrict__ out, unsigned short* __restrict__ hb,
             float* __restrict__ ss, float* __restrict__ sd,
             int nrows,
             const float* __restrict__ g1, const float* __restrict__ g2,
             const float* __restrict__ g3,
             const int* __restrict__ i1, const int* __restrict__ i2,
             const int* __restrict__ i3) {
  __shared__ float ers[32][KD];
  int t = threadIdx.x;
  int row0 = blockIdx.x * 32;
  const float* Wm = (MODE == 1 && blockIdx.x >= (gridDim.x >> 1)) ? Wb : Wa;
  for (int i = t; i < 32*KD; i += 256) {
    int r = i >> 7, k = i & 127;
    int gr = row0 + r;
    float val;
    if (MODE == 3) {
      const float* srow;
      if (gr < NS)           srow = g1 + (size_t)i1[gr]*KD;
      else if (gr < NS + NE) srow = g2 + (size_t)i2[gr - NS]*KD;
      else                   srow = g3 + (size_t)i3[gr - NS - NE]*KD;
      val = srow[k];
    } else if (MODE == 2) {
      val = g1[(size_t)i1[gr]*KD + k] - g1[(size_t)(NS + i2[gr])*KD + k];
    } else {
      val = (gr < nrows) ? in[(size_t)gr*KD + k] : 0.f;
    }
    ers[r][k] = val;
  }
  __syncthreads();
  int w = t >> 6, c = t & 63;
  float acc0[8] = {0,0,0,0,0,0,0,0}, acc1[8] = {0,0,0,0,0,0,0,0};
  #pragma unroll 2
  for (int kc = 0; kc < KD; kc += 4) {
    float wa[4], wb[4];
    #pragma unroll
    for (int j = 0; j < 4; j++) {
      wa[j] = Wm[(kc + j)*KD + c];
      wb[j] = Wm[(kc + j)*KD + c + 64];
    }
    #pragma unroll
    for (int r = 0; r < 8; r++) {
      float4 e = *(const float4*)&ers[w*8 + r][kc];   // wave-uniform broadcast read
      acc0[r] += e.x*wa[0] + e.y*wa[1] + e.z*wa[2] + e.w*wa[3];
      acc1[r] += e.x*wb[0] + e.y*wb[1] + e.z*wb[2] + e.w*wb[3];
    }
  }
  if (MODE == 0 || MODE == 3) {
    float as1 = v1[c], as2 = v1[c + 64], ad1 = v2[c], ad2 = v2[c + 64];
    #pragma unroll
    for (int r = 0; r < 8; r++) {
      int gr = row0 + w*8 + r;
      if (gr < nrows) {
        hb[(size_t)gr*KD + c]      = f2b_(acc0[r]);
        hb[(size_t)gr*KD + c + 64] = f2b_(acc1[r]);
      }
      float s = acc0[r]*as1 + acc1[r]*as2;
      float d = acc0[r]*ad1 + acc1[r]*ad2;
      #pragma unroll
      for (int off = 32; off; off >>= 1) { s += __shfl_xor(s, off); d += __shfl_xor(d, off); }
      if (c == 0 && gr < nrows) { ss[gr] = s; sd[gr] = d; }
    }
  } else if (MODE == 1) {
    #pragma unroll
    for (int r = 0; r < 8; r++) {
      int gr = row0 + w*8 + r;
      if (gr < nrows) {
        out[(size_t)gr*KD + c] = sigm_(acc0[r]);
        out[(size_t)gr*KD + c + 64] = sigm_(acc1[r]);
      }
    }
  } else {
    float b1 = v1[c], b2 = v1[c + 64];
    #pragma unroll
    for (int r = 0; r < 8; r++) {
      int gr = row0 + w*8 + r;
      float kr1 = v2[(size_t)gr*KD + c], kr2 = v2[(size_t)gr*KD + c + 64];
      float o1 = sigm_(acc0[r] + b1), o2 = sigm_(acc1[r] + b2);
      float num = o1*kr1 + o2*kr2, den = kr1 + kr2;
      #pragma unroll
      for (int off = 32; off; off >>= 1) { num += __shfl_xor(num, off); den += __shfl_xor(den, off); }
      if (c == 0) out[gr] = num/den;
    }
  }
}

// ---------- segment-softmax aggregation, 3 graphs batched ----------
// bf16 messages (256B rows): 4 edge-subgroups x 16 feature-lanes, ONE 16B load
// per lane per edge. Single-pass softmax (scores bounded).
// Zo == nullptr => layer 1; Zo != nullptr => layer 2 (skip k rows; g0 -> fp32
// eout, g1/g2 -> fused normalize+bf16 Z only)
__global__ void k_agg(const int* __restrict__ rp_all, const unsigned short* __restrict__ col_all,
                      const unsigned short* __restrict__ hb_base, const float* __restrict__ ss,
                      const float* __restrict__ sd, float* __restrict__ out,
                      unsigned short* __restrict__ Zo) {
  int gw = blockIdx.x*4 + (threadIdx.x >> 6);
  int lane = threadIdx.x & 63;
  if (gw >= 3*NNODE) return;
  int g = gw / NNODE;
  int node = gw - g*NNODE;
  bool layer2 = (Zo != nullptr);
  if (layer2 && node >= NS + NE) return;        // k rows unused after layer 2
  const int* rp = rp_all + g*RP;
  const unsigned short* cl = col_all + (size_t)g*NCSR;
  const unsigned short* hgb = layer2 ? hb_base + (size_t)g*NNODE*KD : hb_base;
  const float* ssg = layer2 ? ss + g*NNODE : ss;
  const float* sdg = layer2 ? sd + g*NNODE : sd;
  int e0 = rp[node], e1 = rp[node + 1];
  float sdv = sdg[node];
  int sub = lane >> 4;       // edge subgroup 0..3
  int fl  = lane & 15;       // feature lane: features fl*8 .. fl*8+7
  float l = 0.f;
  float A[8] = {0,0,0,0,0,0,0,0};
  for (int base = e0; base < e1; base += 64) {
    int e = base + lane;
    float p = 0.f; int o = 0;
    if (e < e1) { o = cl[e]; p = __expf(lrelu_(ssg[o] + sdv)); }
    l += p;
    int cnt = min(64, e1 - base);
    #pragma unroll 4
    for (int j = 0; j*4 < cnt; j++) {
      int idx = j*4 + sub;
      float pj = __shfl(p, idx);
      int oj = __shfl(o, idx);
      if (idx < cnt) {
        short8 mv = *(const short8*)&hgb[(size_t)oj*KD + fl*8];   // 16B = 8 bf16
        #pragma unroll
        for (int q = 0; q < 8; q++)
          A[q] += pj * bf2f_((unsigned short)mv[q]);
      }
    }
  }
  #pragma unroll
  for (int off = 32; off; off >>= 1) l += __shfl_xor(l, off);
  #pragma unroll
  for (int q = 0; q < 8; q++) {
    A[q] += __shfl_xor(A[q], 16);
    A[q] += __shfl_xor(A[q], 32);
  }
  float inv = 1.f/(l + 1e-16f);
  float av[8];
  #pragma unroll
  for (int q = 0; q < 8; q++) av[q] = elu_(A[q]*inv);
  if (!layer2 || g == 0) {
    if (sub == 0) {
      float* orow = &out[(size_t)gw*KD + fl*8];
      *(float4*)orow       = make_float4(av[0], av[1], av[2], av[3]);
      *(float4*)(orow + 4) = make_float4(av[4], av[5], av[6], av[7]);
    }
  }
  if (layer2 && g >= 1) {
    // fused normalize + bf16 cast
    float nrm = av[0]*av[0] + av[1]*av[1] + av[2]*av[2] + av[3]*av[3]
              + av[4]*av[4] + av[5]*av[5] + av[6]*av[6] + av[7]*av[7];
    #pragma unroll
    for (int off = 1; off <= 8; off <<= 1) nrm += __shfl_xor(nrm, off);
    float invn = 1.f/(sqrtf(nrm) + 1e-12f);
    if (sub == 0) {
      unsigned short* zr = Zo + ((size_t)(g - 1)*8192 + node)*KD + fl*8;
      ushort4 u0, u1;
      u0.x = f2b_(av[0]*invn); u0.y = f2b_(av[1]*invn);
      u0.z = f2b_(av[2]*invn); u0.w = f2b_(av[3]*invn);
      u1.x = f2b_(av[4]*invn); u1.y = f2b_(av[5]*invn);
      u1.z = f2b_(av[6]*invn); u1.w = f2b_(av[7]*invn);
      *(ushort4*)zr = u0;
      *(ushort4*)(zr + 4) = u1;
    }
  }
}

// ---------- bf16 MFMA similarity GEMM with fused exp/rowsum/colsum/diag ----------
__global__ __launch_bounds__(256)
void k_sim(const unsigned short* __restrict__ Z, float* __restrict__ zbuf,
           float* __restrict__ dg_all) {
  __shared__ unsigned short As[128*KD];   // 32 KB, row r: 16 groups of 8, group g at (g ^ (r&15))
  __shared__ unsigned short Bs[128*KD];   // 32 KB
  int z = blockIdx.z;
  int t = threadIdx.x;
  const unsigned short* Arow = Z + ((size_t)z*NS + (size_t)blockIdx.x*128)*KD;
  const unsigned short* Brow = Z + ((size_t)8192 + (size_t)z*NS + (size_t)blockIdx.y*128)*KD;
  #pragma unroll
  for (int j = 0; j < 8; j++) {
    int G = t + j*256;                     // linear 16B-group id, 0..2047
    int r = G >> 4, g = G & 15;
    int sw = g ^ (r & 15);
    *(float4*)&As[(r*16 + sw)*8] = *(const float4*)&Arow[(size_t)G*8];
    *(float4*)&Bs[(r*16 + sw)*8] = *(const float4*)&Brow[(size_t)G*8];
  }
  __syncthreads();
  int w = t >> 6, lane = t & 63;
  int rw = (w >> 1)*64, cw = (w & 1)*64;
  int m15 = lane & 15, quad = lane >> 4;
  float4_ acc[4][4] = {};
  #pragma unroll
  for (int kq = 0; kq < 4; kq++) {
    short8 a[4], b[4];
    int g = kq*4 + quad;
    #pragma unroll
    for (int mi = 0; mi < 4; mi++) {
      int r = rw + mi*16 + m15;
      a[mi] = *(const short8*)&As[(r*16 + (g ^ (r & 15)))*8];
    }
    #pragma unroll
    for (int ni = 0; ni < 4; ni++) {
      int r = cw + ni*16 + m15;
      b[ni] = *(const short8*)&Bs[(r*16 + (g ^ (r & 15)))*8];
    }
    #pragma unroll
    for (int mi = 0; mi < 4; mi++)
      #pragma unroll
      for (int ni = 0; ni < 4; ni++)
        acc[mi][ni] = __builtin_amdgcn_mfma_f32_16x16x32_bf16(a[mi], b[ni], acc[mi][ni], 0, 0, 0);
  }
  int i0 = blockIdx.x*128, j0 = blockIdx.y*128;
  float* rowsum = zbuf + z*NS;
  float* colsum = zbuf + 2*NS + z*NS;
  float* diag = dg_all + z*NS;
  float cs[4] = {0,0,0,0};
  #pragma unroll
  for (int mi = 0; mi < 4; mi++) {
    float rs[4] = {0,0,0,0};
    #pragma unroll
    for (int ni = 0; ni < 4; ni++) {
      #pragma unroll
      for (int reg = 0; reg < 4; reg++) {
        float sim2 = acc[mi][ni][reg]*2.0f;
        int gi = i0 + rw + mi*16 + quad*4 + reg;     // C/D: row=(lane>>4)*4+reg
        int gj = j0 + cw + ni*16 + m15;              //      col=lane&15
        if (gi == gj) diag[gi] = sim2;
        float e = __expf(sim2);
        rs[reg] += e; cs[ni] += e;
      }
    }
    #pragma unroll
    for (int reg = 0; reg < 4; reg++) {
      float v = rs[reg];
      v += __shfl_xor(v, 1); v += __shfl_xor(v, 2);
      v += __shfl_xor(v, 4); v += __shfl_xor(v, 8);
      if (m15 == 0) atomicAdd(&rowsum[i0 + rw + mi*16 + quad*4 + reg], v);
    }
  }
  #pragma unroll
  for (int ni = 0; ni < 4; ni++) {
    float v = cs[ni];
    v += __shfl_xor(v, 16); v += __shfl_xor(v, 32);
    if (quad == 0) atomicAdd(&colsum[j0 + cw + ni*16 + m15], v);
  }
}

// single block; writes closs directly to out[BQ]
__global__ void k_loss(const float* __restrict__ zbuf, const float* __restrict__ dg_all,
                       float* __restrict__ out) {
  __shared__ float red[256];
  int t = threadIdx.x;
  float v = 0.f;
  for (int z = 0; z < 2; z++)
    for (int i = t; i < NS; i += 256)
      v += logf(zbuf[z*NS + i]) + logf(zbuf[2*NS + z*NS + i]) - 2.f*dg_all[z*NS + i];
  red[t] = v; __syncthreads();
  for (int off = 128; off > 0; off >>= 1) {
    if (t < off) red[t] += red[t + off];
    __syncthreads();
  }
  if (t == 0) out[BQ] = 0.1f*red[0]/(float)NS;
}

extern "C" void kernel_launch(void* const* d_in, const int* in_sizes, int n_in,
                              void* d_out, int out_size, void* d_ws, size_t ws_size,
                              hipStream_t stream) {
  const float* E_stu  = (const float*)d_in[0];
  const float* E_exer = (const float*)d_in[1];
  const float* E_k    = (const float*)d_in[2];
  const float* W1  = (const float*)d_in[3];
  const float* a1s = (const float*)d_in[4];
  const float* a1d = (const float*)d_in[5];
  const float* W2  = (const float*)d_in[6];
  const float* a2s = (const float*)d_in[7];
  const float* a2d = (const float*)d_in[8];
  const float* pW1 = (const float*)d_in[9];
  const float* pW2 = (const float*)d_in[10];
  const float* pW3 = (const float*)d_in[11];
  const float* pb3 = (const float*)d_in[12];
  const float* kn_r = (const float*)d_in[13];
  const int* stu_ids  = (const int*)d_in[14];
  const int* exer_ids = (const int*)d_in[15];
  const int* k_ids    = (const int*)d_in[16];
  EdgePtrs ep;
  for (int g = 0; g < 3; g++) {
    ep.s_src[g] = (const int*)d_in[17 + g*4];
    ep.s_dst[g] = (const int*)d_in[18 + g*4];
    ep.e_src[g] = (const int*)d_in[19 + g*4];
    ep.e_dst[g] = (const int*)d_in[20 + g*4];
  }
  const int* stu_index  = (const int*)d_in[29];
  const int* exer_index = (const int*)d_in[30];
  float* out = (float*)d_out;   // [0..8191] predictions, [8192] closs

  // ---- workspace carve ----
  char* p = (char*)d_ws;
  auto carve = [&](size_t bytes) -> char* {
    char* r = p; p += (bytes + 255) & ~(size_t)255; return r;
  };
  const size_t NODE_F = (size_t)NNODE*KD;
  // attention scores fp32 (small)
  float* ssb = (float*)carve((size_t)8*NNODE*4);
  float* ss0 = ssb,            *sd0 = ssb + NNODE;
  float* ss3 = ssb + 2*NNODE,  *sd3 = ssb + 5*NNODE;
  // bf16 message tables
  unsigned short* hb0 = (unsigned short*)carve(NODE_F*2);        // layer-1 h (shared)
  unsigned short* hb3 = (unsigned short*)carve(3*NODE_F*2);      // layer-2 h x3
  // time-multiplexed region: CSR partials -> layer-1 agg out -> head PD
  float* Creg = (float*)carve(3*NODE_F*4);   // 12.8 MB
  int*   part = (int*)Creg;                  //   part[3][HB][NNODE] (3.2 MB)
  int*   boff = (int*)Creg + (size_t)3*HB*NNODE;  // boff[3][HB][NNODE] (3.2 MB)
  float* etmp3 = Creg;                       //   layer-1 agg output x3 (12.8 MB)
  float* PD = Creg;                          //   head P|D (4.2 MB)
  float* eoutAll = (float*)carve((size_t)(NS + NE)*KD*4);        // main-graph layer-2 out
  int* cnt_all = (int*)carve((size_t)3*NNODE*4);
  int* rp_all  = (int*)carve((size_t)3*RP*4);
  unsigned short* col_all = (unsigned short*)carve((size_t)3*NCSR*2);
  float* pWT = (float*)carve((size_t)3*KD*KD*4);
  float* pW1T = pWT, *pW2T = pWT + KD*KD, *pW3T = pWT + 2*KD*KD;
  float* zbuf = (float*)carve((size_t)4*NS*4);     // rs[2][NS], cs[2][NS]
  float* dg_all = (float*)carve((size_t)2*NS*4);
  unsigned short* Z = (unsigned short*)carve((size_t)2*8192*KD*2);  // bf16 Z1|Z2

  // ---- zero init (ws poisoned 0xAA every launch; only zbuf needs zeros) ----
  hipMemsetAsync(zbuf, 0, (size_t)4*NS*4, stream);

  // ---- CSR build (atomic-free, all stages parallel) + weight transpose ----
  k_hist<<<dim3(HB, 3), 256, 0, stream>>>(ep, part);
  k_sumpart<<<(3*NNODE + 255)/256, 256, 0, stream>>>(part, cnt_all);
  k_scan<<<3, 1024, 0, stream>>>(cnt_all, rp_all);
  k_boff<<<(3*NNODE + 255)/256, 256, 0, stream>>>(part, rp_all, boff);
  k_scatter<<<dim3(HB, 3), 256, 0, stream>>>(ep, boff, col_all);
  k_tr<<<dim3(4, 4, 3), dim3(32, 8), 0, stream>>>(pW1, pW2, pW3, pWT);

  // ---- GAT layer 1 (h shared across graphs; embedding gather fused; bf16 h) ----
  k_ngemm<3><<<NNODE/32, 256, 0, stream>>>(nullptr, W1, nullptr, a1s, a1d,
                                           nullptr, hb0, ss0, sd0, NNODE,
                                           E_stu, E_exer, E_k, stu_ids, exer_ids, k_ids);
  k_agg<<<3*NNODE/4, 256, 0, stream>>>(rp_all, col_all, hb0, ss0, sd0, etmp3, nullptr);

  // ---- GAT layer 2 ----
  k_ngemm<0><<<3*NNODE/32, 256, 0, stream>>>(etmp3, W2, nullptr, a2s, a2d,
                                             nullptr, hb3, ss3, sd3, 3*NNODE,
                                             nullptr, nullptr, nullptr, nullptr, nullptr, nullptr);
  k_agg<<<3*NNODE/4, 256, 0, stream>>>(rp_all, col_all, hb3, ss3, sd3, eoutAll, Z);

  // ---- contrastive loss (bf16 MFMA sim) ----
  k_sim<<<dim3(32, 32, 2), 256, 0, stream>>>(Z, zbuf, dg_all);
  k_loss<<<1, 256, 0, stream>>>(zbuf, dg_all, out);

  // ---- prediction head ----
  k_ngemm<1><<<(2*NS)/32, 256, 0, stream>>>(eoutAll, pW1T, pW2T, pb3, kn_r, PD,
                                            nullptr, nullptr, nullptr, 2*NS,
                                            nullptr, nullptr, nullptr, nullptr, nullptr, nullptr);
  k_ngemm<2><<<BQ/32, 256, 0, stream>>>(nullptr, pW3T, nullptr, pb3, kn_r, out,
                                        nullptr, nullptr, nullptr, BQ,
                                        PD, nullptr, nullptr, stu_index, exer_index, nullptr);
}